// Round 9
// baseline (344.678 us; speedup 1.0000x reference)
//
#include <hip/hip_runtime.h>
#include <hip/hip_bf16.h>

typedef __attribute__((ext_vector_type(8))) short short8;
typedef __attribute__((ext_vector_type(4))) float f32x4;
typedef unsigned short u16;
typedef unsigned int u32;

#define NROWS 16384
#define KDIM 16384
#define EPS 1e-6f

__device__ __forceinline__ u16 f2bf(float x) {
    union { float f; u32 u; } v; v.f = x;
    u32 u = v.u;
    u32 r = (u + 0x7FFFu + ((u >> 16) & 1u)) >> 16;  // RNE
    return (u16)r;
}

__device__ __forceinline__ void glds16(const void* g, void* l) {
    __builtin_amdgcn_global_load_lds(
        (const __attribute__((address_space(1))) void*)g,
        (__attribute__((address_space(3))) void*)l, 16, 0, 0);
}

__device__ __forceinline__ short cvbf(float x) {
    __hip_bfloat16 h = __float2bfloat16(x);
    return *(short*)&h;
}

// ---------------- Stage 0: transpose weight -> Wt[64][256] ----------------
__global__ __launch_bounds__(256) void wt_kernel(const float* __restrict__ W,
                                                 float* __restrict__ Wt) {
    int idx = blockIdx.x * 256 + threadIdx.x;  // 16384
    int k = idx >> 6, c = idx & 63;
    Wt[c * 256 + k] = W[idx];
}

// ---------------- Stage 1: support = input @ W (fp32) ---------------------
__global__ __launch_bounds__(256) void support_kernel(
    const float* __restrict__ inp, const float* __restrict__ Wt,
    float* __restrict__ sup)
{
    int tid = threadIdx.x;
    int col = tid & 63;
    int rr = tid >> 6;                        // 0..3
    int rowbase = blockIdx.x * 32 + rr * 8;   // 8 rows per thread
    const float4* wt4 = (const float4*)(Wt + (size_t)col * 256);
    float acc[8];
#pragma unroll
    for (int i = 0; i < 8; ++i) acc[i] = 0.f;
    for (int k4 = 0; k4 < 64; ++k4) {
        float4 wv = wt4[k4];
#pragma unroll
        for (int i = 0; i < 8; ++i) {
            float4 iv = *((const float4*)(inp + (size_t)(rowbase + i) * 256) + k4);
            acc[i] += iv.x * wv.x + iv.y * wv.y + iv.z * wv.z + iv.w * wv.w;
        }
    }
#pragma unroll
    for (int i = 0; i < 8; ++i)
        sup[(size_t)(rowbase + i) * 64 + col] = acc[i];
}

// ---------------- Stage 2: global min ------------------------------------
__global__ __launch_bounds__(256) void min_part_kernel(
    const float* __restrict__ sup, float* __restrict__ partmin)
{
    __shared__ float wmin[4];
    int tid = threadIdx.x;
    const float4* s4 = (const float4*)sup;
    size_t idx = (size_t)blockIdx.x * 256 + tid;
    float m = 3.4e38f;
#pragma unroll
    for (int j = 0; j < 4; ++j) {
        float4 v = s4[idx + (size_t)j * 65536];
        m = fminf(m, fminf(fminf(v.x, v.y), fminf(v.z, v.w)));
    }
#pragma unroll
    for (int off = 32; off; off >>= 1) m = fminf(m, __shfl_down(m, off, 64));
    if ((tid & 63) == 0) wmin[tid >> 6] = m;
    __syncthreads();
    if (tid == 0)
        partmin[blockIdx.x] = fminf(fminf(wmin[0], wmin[1]), fminf(wmin[2], wmin[3]));
}

__global__ __launch_bounds__(256) void min_final_kernel(
    const float* __restrict__ partmin, float* __restrict__ mu)
{
    __shared__ float wmin[4];
    int tid = threadIdx.x;
    float m = partmin[tid];
#pragma unroll
    for (int off = 32; off; off >>= 1) m = fminf(m, __shfl_down(m, off, 64));
    if ((tid & 63) == 0) wmin[tid >> 6] = m;
    __syncthreads();
    if (tid == 0)
        mu[0] = fminf(fminf(wmin[0], wmin[1]), fminf(wmin[2], wmin[3]));
}

// ---------------- Stage 3: Bt[n][k] bf16; n<64: s^(p+1), n>=64: s^p -------
__global__ __launch_bounds__(256) void build_bt_kernel(
    const float* __restrict__ sup, const float* __restrict__ muptr,
    const int* __restrict__ pptr, u16* __restrict__ Bt)
{
    int k = blockIdx.x * 256 + threadIdx.x;   // 0..16383
    float mu = *muptr;
    int p = *pptr;
    const float4* srow = (const float4*)(sup + (size_t)k * 64);
#pragma unroll
    for (int j = 0; j < 16; ++j) {
        float4 v = srow[j];
        float ss[4] = {v.x, v.y, v.z, v.w};
#pragma unroll
        for (int q = 0; q < 4; ++q) {
            int c = j * 4 + q;
            float s = ss[q] - mu + EPS;
            float d = 1.f;
            for (int i = 0; i < p; ++i) d *= s;   // s^p
            Bt[(size_t)c * KDIM + k] = f2bf(d * s);          // top
            Bt[(size_t)(c + 64) * KDIM + k] = f2bf(d);       // down
        }
    }
}

// ---------------- Stage 4: GEMM partials, K-split=8 -----------------------
// R8 skeleton verbatim (BM=64, BN=128, BK=64, 512 thr, 2 blocks/CU, bf16 A
// via depth-2 reg pipeline, B via glds, depth-1 LDS dbuf, 2Mx4N waves).
// ONLY change: K-split 2 -> 8. Grid 2048 = 256 rowgroups x 8 K-slices;
// kq = blockIdx&7 pins each XCD (round-robin dispatch) to ONE 512 KB Bt
// slice -> L2-resident (re-touched every ~0.65us, ~0.45MB adj streams by,
// vs 4MB L2) -> Bt HBM re-fetch ~0 (was ~0.6 GB at K-split=2).
#define BM 64
#define BN 128
#define BK 64
#define KS 2048            // K-slice length
#define NTI 32             // KS/BK

__global__ __launch_bounds__(512, 4) void gemm_kernel(
    const float* __restrict__ adj, const u16* __restrict__ Bt,
    float* __restrict__ Pp)
{
    __shared__ __align__(16) u16 Ash[2][BM * BK];   //  8 KB x2 (bf16)
    __shared__ __align__(16) u16 Bsh[2][BN * BK];   // 16 KB x2 (bf16)

    const int tid = threadIdx.x;
    const int kq = blockIdx.x & 7;           // XCD-pinned K-slice
    const int rb = blockIdx.x >> 3;          // rowgroup 0..255
    const size_t rowbase = (size_t)rb * BM;
    const size_t kbase   = (size_t)kq * KS;

    // --- A staging: 512 granules (16 B bf16 = 8 floats), 8 granules/row.
    const int ar = tid >> 3, ac = tid & 7;
    const float* asrc = adj + (rowbase + ar) * KDIM + kbase + ac * 8;
    const int awslot = ar * 8 + (ac ^ (ar & 7));

    // --- B staging (glds, linear dest + inverse-swizzled source)
    const int ga0 = tid, ga1 = tid + 512;
    const int bn0 = ga0 >> 3, bx0 = (ga0 & 7) ^ (bn0 & 7);
    const int bn1 = ga1 >> 3, bx1 = (ga1 & 7) ^ (bn1 & 7);
    const u16* bsrc0 = Bt + (size_t)bn0 * KDIM + kbase + bx0 * 8;
    const u16* bsrc1 = Bt + (size_t)bn1 * KDIM + kbase + bx1 * 8;

    // --- compute indices: 8 waves = 2M x 4N
    const int lane = tid & 63;
    const int w    = tid >> 6;
    const int wm   = w >> 2;                // 0..1 : 32-row half
    const int wn   = w & 3;                 // 0..3 : 16-col group
    const int l15  = lane & 15, lg = lane >> 4;
    const int arow0 = wm * 32 + l15;
    const int arow1 = arow0 + 16;
    const int asw   = arow0 & 7;
    const int n0    = wn * 16 + l15;        // top col; down = n0+64
    const int nd    = n0 + 64;
    const int bsw   = n0 & 7;

    f32x4 acc00 = {0.f, 0.f, 0.f, 0.f};
    f32x4 acc01 = acc00, acc10 = acc00, acc11 = acc00;

    auto gldsB = [&](int kt, int buf) {
        char* bb = (char*)Bsh[buf];
        const int koff = kt * BK;
        glds16(bsrc0 + koff, bb + ga0 * 16);
        glds16(bsrc1 + koff, bb + ga1 * 16);
    };
    auto loadA = [&](int kt, float4& x, float4& y) {
        const float4* p = (const float4*)(asrc + kt * BK);
        x = p[0]; y = p[1];
    };
    auto writeA = [&](const float4& x, const float4& y, int buf) {
        uint4 v;
        v.x = (u32)(u16)cvbf(x.x) | ((u32)(u16)cvbf(x.y) << 16);
        v.y = (u32)(u16)cvbf(x.z) | ((u32)(u16)cvbf(x.w) << 16);
        v.z = (u32)(u16)cvbf(y.x) | ((u32)(u16)cvbf(y.y) << 16);
        v.w = (u32)(u16)cvbf(y.z) | ((u32)(u16)cvbf(y.w) << 16);
        ((uint4*)Ash[buf])[awslot] = v;
    };
    auto compute = [&](int buf) {
        const short8* As8 = (const short8*)Ash[buf];
        const short8* Bs8 = (const short8*)Bsh[buf];
#pragma unroll
        for (int ks = 0; ks < 2; ++ks) {
            const int g = ks * 4 + lg;
            short8 a0 = As8[arow0 * 8 + (g ^ asw)];
            short8 a1 = As8[arow1 * 8 + (g ^ asw)];
            short8 bt_ = Bs8[n0 * 8 + (g ^ bsw)];
            short8 bd_ = Bs8[nd * 8 + (g ^ bsw)];
            acc00 = __builtin_amdgcn_mfma_f32_16x16x32_bf16(a0, bt_, acc00, 0, 0, 0);
            acc01 = __builtin_amdgcn_mfma_f32_16x16x32_bf16(a0, bd_, acc01, 0, 0, 0);
            acc10 = __builtin_amdgcn_mfma_f32_16x16x32_bf16(a1, bt_, acc10, 0, 0, 0);
            acc11 = __builtin_amdgcn_mfma_f32_16x16x32_bf16(a1, bd_, acc11, 0, 0, 0);
        }
    };

    float4 pa0, pa1;   // A-reg set holding tile t+1 (even iters)
    float4 pb0, pb1;   // A-reg set holding tile t+2 in flight

    // prologue
    loadA(0, pa0, pa1);
    gldsB(0, 0);
    writeA(pa0, pa1, 0);
    loadA(1, pa0, pa1);
    __syncthreads();          // tile 0 resident

    for (int tt = 0; tt < NTI; tt += 2) {
        // ---- even iter: compute tile tt from buf0; A-regs pa = tile tt+1
        if (tt + 1 < NTI) gldsB(tt + 1, 1);
        if (tt + 2 < NTI) loadA(tt + 2, pb0, pb1);
        compute(0);
        if (tt + 1 < NTI) writeA(pa0, pa1, 1);
        __syncthreads();
        // ---- odd iter: compute tile tt+1 from buf1; A-regs pb = tile tt+2
        if (tt + 2 < NTI) gldsB(tt + 2, 0);
        if (tt + 3 < NTI) loadA(tt + 3, pa0, pa1);
        compute(1);
        if (tt + 2 < NTI) writeA(pb0, pb1, 0);
        __syncthreads();
    }

    // partial store: [block][64 rows][128 cols]; C: col=l15 base, row=lg*4+q
    float* pb = Pp + (size_t)blockIdx.x * (BM * BN);
#pragma unroll
    for (int q = 0; q < 4; ++q) {
        int r0 = wm * 32 + lg * 4 + q;
        int r1 = r0 + 16;
        pb[r0 * BN + n0] = acc00[q];
        pb[r0 * BN + nd] = acc01[q];
        pb[r1 * BN + n0] = acc10[q];
        pb[r1 * BN + nd] = acc11[q];
    }
}

// ---------------- Stage 5: combine 8 K-slices, ratio + mu + bias ----------
// Pp layout: block b = rb*8 + kq : [b][64][128]
__global__ __launch_bounds__(256) void reduce_kernel(
    const float* __restrict__ Pp, const float* __restrict__ bias,
    const float* __restrict__ muptr, float* __restrict__ out)
{
    int idx = blockIdx.x * 256 + threadIdx.x;   // 1M outputs
    int r = idx >> 6, c = idx & 63;
    int rb = r >> 6, rr = r & 63;
    const float* p = Pp + (size_t)(rb * 8) * (BM * BN) + rr * BN + c;
    float T = 0.f, D = 0.f;
#pragma unroll
    for (int kq = 0; kq < 8; ++kq) {
        T += p[(size_t)kq * (BM * BN)];
        D += p[(size_t)kq * (BM * BN) + 64];
    }
    out[idx] = T / D + muptr[0] + bias[c];
}

extern "C" void kernel_launch(void* const* d_in, const int* in_sizes, int n_in,
                              void* d_out, int out_size, void* d_ws, size_t ws_size,
                              hipStream_t stream)
{
    const float* inp  = (const float*)d_in[0];
    const float* adj  = (const float*)d_in[1];
    const float* W    = (const float*)d_in[2];
    const float* bias = (const float*)d_in[3];
    const int*   p    = (const int*)d_in[4];
    float* out = (float*)d_out;

    // ws layout: Bt 4MB | partmin 1KB | mu | Wt 64KB | (8MB:) Pp 64MB
    char* ws = (char*)d_ws;
    u16*   Bt      = (u16*)ws;
    float* partmin = (float*)(ws + (size_t)4 * 1024 * 1024);
    float* mu      = partmin + 256;
    float* Wt      = (float*)(ws + (size_t)4 * 1024 * 1024 + 4096);
    float* Pp      = (float*)(ws + (size_t)8 * 1024 * 1024);

    float* sup = out;   // park support in d_out; reduce overwrites at the end

    wt_kernel       <<<64,   256, 0, stream>>>(W, Wt);
    support_kernel  <<<512,  256, 0, stream>>>(inp, Wt, sup);
    min_part_kernel <<<256,  256, 0, stream>>>(sup, partmin);
    min_final_kernel<<<1,    256, 0, stream>>>(partmin, mu);
    build_bt_kernel <<<64,   256, 0, stream>>>(sup, mu, p, Bt);
    gemm_kernel     <<<2048, 512, 0, stream>>>(adj, Bt, Pp);
    reduce_kernel   <<<4096, 256, 0, stream>>>(Pp, bias, mu, out);
}

// Round 10
// 314.486 us; speedup vs baseline: 1.0960x; 1.0960x over previous
//
#include <hip/hip_runtime.h>
#include <hip/hip_bf16.h>

typedef __attribute__((ext_vector_type(8))) short short8;
typedef __attribute__((ext_vector_type(4))) float f32x4;
typedef unsigned short u16;
typedef unsigned int u32;

#define NROWS 16384
#define KDIM 16384
#define EPS 1e-6f

__device__ __forceinline__ u16 f2bf(float x) {
    union { float f; u32 u; } v; v.f = x;
    u32 u = v.u;
    u32 r = (u + 0x7FFFu + ((u >> 16) & 1u)) >> 16;  // RNE
    return (u16)r;
}

__device__ __forceinline__ void glds16(const void* g, void* l) {
    __builtin_amdgcn_global_load_lds(
        (const __attribute__((address_space(1))) void*)g,
        (__attribute__((address_space(3))) void*)l, 16, 0, 0);
}

__device__ __forceinline__ short cvbf(float x) {
    __hip_bfloat16 h = __float2bfloat16(x);
    return *(short*)&h;
}

// ---------------- Stage 0: transpose weight -> Wt[64][256] ----------------
__global__ __launch_bounds__(256) void wt_kernel(const float* __restrict__ W,
                                                 float* __restrict__ Wt) {
    int idx = blockIdx.x * 256 + threadIdx.x;  // 16384
    int k = idx >> 6, c = idx & 63;
    Wt[c * 256 + k] = W[idx];
}

// ---------------- Stage 1: support = input @ W (fp32) ---------------------
__global__ __launch_bounds__(256) void support_kernel(
    const float* __restrict__ inp, const float* __restrict__ Wt,
    float* __restrict__ sup)
{
    int tid = threadIdx.x;
    int col = tid & 63;
    int rr = tid >> 6;                        // 0..3
    int rowbase = blockIdx.x * 32 + rr * 8;   // 8 rows per thread
    const float4* wt4 = (const float4*)(Wt + (size_t)col * 256);
    float acc[8];
#pragma unroll
    for (int i = 0; i < 8; ++i) acc[i] = 0.f;
    for (int k4 = 0; k4 < 64; ++k4) {
        float4 wv = wt4[k4];
#pragma unroll
        for (int i = 0; i < 8; ++i) {
            float4 iv = *((const float4*)(inp + (size_t)(rowbase + i) * 256) + k4);
            acc[i] += iv.x * wv.x + iv.y * wv.y + iv.z * wv.z + iv.w * wv.w;
        }
    }
#pragma unroll
    for (int i = 0; i < 8; ++i)
        sup[(size_t)(rowbase + i) * 64 + col] = acc[i];
}

// ---------------- Stage 2: global min ------------------------------------
__global__ __launch_bounds__(256) void min_part_kernel(
    const float* __restrict__ sup, float* __restrict__ partmin)
{
    __shared__ float wmin[4];
    int tid = threadIdx.x;
    const float4* s4 = (const float4*)sup;
    size_t idx = (size_t)blockIdx.x * 256 + tid;
    float m = 3.4e38f;
#pragma unroll
    for (int j = 0; j < 4; ++j) {
        float4 v = s4[idx + (size_t)j * 65536];
        m = fminf(m, fminf(fminf(v.x, v.y), fminf(v.z, v.w)));
    }
#pragma unroll
    for (int off = 32; off; off >>= 1) m = fminf(m, __shfl_down(m, off, 64));
    if ((tid & 63) == 0) wmin[tid >> 6] = m;
    __syncthreads();
    if (tid == 0)
        partmin[blockIdx.x] = fminf(fminf(wmin[0], wmin[1]), fminf(wmin[2], wmin[3]));
}

__global__ __launch_bounds__(256) void min_final_kernel(
    const float* __restrict__ partmin, float* __restrict__ mu)
{
    __shared__ float wmin[4];
    int tid = threadIdx.x;
    float m = partmin[tid];
#pragma unroll
    for (int off = 32; off; off >>= 1) m = fminf(m, __shfl_down(m, off, 64));
    if ((tid & 63) == 0) wmin[tid >> 6] = m;
    __syncthreads();
    if (tid == 0)
        mu[0] = fminf(fminf(wmin[0], wmin[1]), fminf(wmin[2], wmin[3]));
}

// ---------------- Stage 3: Bt[n][k] bf16; n<64: s^(p+1), n>=64: s^p -------
__global__ __launch_bounds__(256) void build_bt_kernel(
    const float* __restrict__ sup, const float* __restrict__ muptr,
    const int* __restrict__ pptr, u16* __restrict__ Bt)
{
    int k = blockIdx.x * 256 + threadIdx.x;   // 0..16383
    float mu = *muptr;
    int p = *pptr;
    const float4* srow = (const float4*)(sup + (size_t)k * 64);
#pragma unroll
    for (int j = 0; j < 16; ++j) {
        float4 v = srow[j];
        float ss[4] = {v.x, v.y, v.z, v.w};
#pragma unroll
        for (int q = 0; q < 4; ++q) {
            int c = j * 4 + q;
            float s = ss[q] - mu + EPS;
            float d = 1.f;
            for (int i = 0; i < p; ++i) d *= s;   // s^p
            Bt[(size_t)c * KDIM + k] = f2bf(d * s);          // top
            Bt[(size_t)(c + 64) * KDIM + k] = f2bf(d);       // down
        }
    }
}

// ---------------- Stage 4: GEMM partials, K-split=2 -----------------------
// R8 skeleton (BM=64, BN=128, BK=64, 512 thr, 2 blocks/CU, bf16-A reg-
// staged, B via glds, 2Mx4N waves) + DEPTH-2 COUNTED-VMCNT pipeline:
// 3 LDS buffers (72 KB -> still 2 blocks/CU), per iter issue {B(t+2) glds,
// A(t+2) reg-loads} then s_waitcnt vmcnt(4) -- completes exactly the 4
// oldest ops = B(t+1)+A(t+1), issued a FULL iteration earlier (latency
// hidden) -- then writeA(t+1), compute(t), lgkmcnt(0), raw s_barrier.
// vmcnt never drains to 0 in the main loop (T4).
#define BM 64
#define BN 128
#define BK 64
#define KH 8192
#define NTI 128   // KH/BK

__global__ __launch_bounds__(512, 4) void gemm_kernel(
    const float* __restrict__ adj, const u16* __restrict__ Bt,
    float* __restrict__ Pp)
{
    __shared__ __align__(16) u16 Ash[3][BM * BK];   //  8 KB x3 (bf16)
    __shared__ __align__(16) u16 Bsh[3][BN * BK];   // 16 KB x3 (bf16)

    const int tid = threadIdx.x;
    const int rb = blockIdx.x >> 1;
    const int h  = blockIdx.x & 1;
    const size_t rowbase = (size_t)rb * BM;
    const size_t kbase   = (size_t)h * KH;

    // --- A staging: 512 granules (16 B bf16 = 8 floats), 8 granules/row
    const int ar = tid >> 3, ac = tid & 7;
    const float* asrc = adj + (rowbase + ar) * KDIM + kbase + ac * 8;
    const int awslot = ar * 8 + (ac ^ (ar & 7));

    // --- B staging (glds, linear dest + inverse-swizzled source)
    const int ga0 = tid, ga1 = tid + 512;
    const int bn0 = ga0 >> 3, bx0 = (ga0 & 7) ^ (bn0 & 7);
    const int bn1 = ga1 >> 3, bx1 = (ga1 & 7) ^ (bn1 & 7);
    const u16* bsrc0 = Bt + (size_t)bn0 * KDIM + kbase + bx0 * 8;
    const u16* bsrc1 = Bt + (size_t)bn1 * KDIM + kbase + bx1 * 8;

    // --- compute indices: 8 waves = 2M x 4N
    const int lane = tid & 63;
    const int w    = tid >> 6;
    const int wm   = w >> 2;                // 0..1 : 32-row half
    const int wn   = w & 3;                 // 0..3 : 16-col group
    const int l15  = lane & 15, lg = lane >> 4;
    const int arow0 = wm * 32 + l15;
    const int arow1 = arow0 + 16;
    const int asw   = arow0 & 7;
    const int n0    = wn * 16 + l15;        // top col; down = n0+64
    const int nd    = n0 + 64;
    const int bsw   = n0 & 7;

    f32x4 acc00 = {0.f, 0.f, 0.f, 0.f};
    f32x4 acc01 = acc00, acc10 = acc00, acc11 = acc00;

    auto gldsB = [&](int kt, int buf) {
        char* bb = (char*)Bsh[buf];
        const int koff = kt * BK;
        glds16(bsrc0 + koff, bb + ga0 * 16);
        glds16(bsrc1 + koff, bb + ga1 * 16);
    };
    auto loadA = [&](int kt, float4& x, float4& y) {
        const float4* p = (const float4*)(asrc + kt * BK);
        x = p[0]; y = p[1];
    };
    auto writeA = [&](const float4& x, const float4& y, int buf) {
        uint4 v;
        v.x = (u32)(u16)cvbf(x.x) | ((u32)(u16)cvbf(x.y) << 16);
        v.y = (u32)(u16)cvbf(x.z) | ((u32)(u16)cvbf(x.w) << 16);
        v.z = (u32)(u16)cvbf(y.x) | ((u32)(u16)cvbf(y.y) << 16);
        v.w = (u32)(u16)cvbf(y.z) | ((u32)(u16)cvbf(y.w) << 16);
        ((uint4*)Ash[buf])[awslot] = v;
    };
    auto compute = [&](int buf) {
        const short8* As8 = (const short8*)Ash[buf];
        const short8* Bs8 = (const short8*)Bsh[buf];
#pragma unroll
        for (int ks = 0; ks < 2; ++ks) {
            const int g = ks * 4 + lg;
            short8 a0 = As8[arow0 * 8 + (g ^ asw)];
            short8 a1 = As8[arow1 * 8 + (g ^ asw)];
            short8 bt_ = Bs8[n0 * 8 + (g ^ bsw)];
            short8 bd_ = Bs8[nd * 8 + (g ^ bsw)];
            acc00 = __builtin_amdgcn_mfma_f32_16x16x32_bf16(a0, bt_, acc00, 0, 0, 0);
            acc01 = __builtin_amdgcn_mfma_f32_16x16x32_bf16(a0, bd_, acc01, 0, 0, 0);
            acc10 = __builtin_amdgcn_mfma_f32_16x16x32_bf16(a1, bt_, acc10, 0, 0, 0);
            acc11 = __builtin_amdgcn_mfma_f32_16x16x32_bf16(a1, bd_, acc11, 0, 0, 0);
        }
    };

    float4 pa0, pa1, pb0, pb1;

    // prologue: establish invariant "4 outstanding = A(t+1),B(t+1)" at t=0
    loadA(0, pa0, pa1);                 // out: A0 A0
    gldsB(0, 0);                        // out: A0 A0 B0 B0
    asm volatile("s_waitcnt vmcnt(2)" ::: "memory");   // A0 done
    writeA(pa0, pa1, 0);
    loadA(1, pa0, pa1);                 // out: B0 B0 A1 A1
    gldsB(1, 1);                        // out: B0 B0 A1 A1 B1 B1
    asm volatile("s_waitcnt vmcnt(4)" ::: "memory");   // B0 done
    asm volatile("s_waitcnt lgkmcnt(0)" ::: "memory");
    __builtin_amdgcn_s_barrier();       // buf0 fully resident

    // iter T: issue B(T+2)->PRE, A(T+2)->L; vmcnt(4) completes A(T+1),B(T+1)
    // (issued at iter T-1); write A(T+1)->NXT; compute CUR; barrier.
#define BODY(T, CUR, NXT, PRE, W0, W1, L0, L1)                          \
    {                                                                   \
        gldsB((T) + 2, (PRE));                                          \
        loadA((T) + 2, L0, L1);                                         \
        asm volatile("s_waitcnt vmcnt(4)" ::: "memory");                \
        writeA(W0, W1, (NXT));                                          \
        compute((CUR));                                                 \
        asm volatile("s_waitcnt lgkmcnt(0)" ::: "memory");              \
        __builtin_amdgcn_s_barrier();                                   \
    }

    // main loop: t = 0..125 (126 = 6*21); bufs cycle t%3, regs by parity
    for (int tt = 0; tt < NTI - 2; tt += 6) {
        BODY(tt + 0, 0, 1, 2, pa0, pa1, pb0, pb1);
        BODY(tt + 1, 1, 2, 0, pb0, pb1, pa0, pa1);
        BODY(tt + 2, 2, 0, 1, pa0, pa1, pb0, pb1);
        BODY(tt + 3, 0, 1, 2, pb0, pb1, pa0, pa1);
        BODY(tt + 4, 1, 2, 0, pa0, pa1, pb0, pb1);
        BODY(tt + 5, 2, 0, 1, pb0, pb1, pa0, pa1);
    }
#undef BODY

    // tail t = 126: nothing left to prefetch; drain, write A(127), compute
    asm volatile("s_waitcnt vmcnt(0)" ::: "memory");
    writeA(pa0, pa1, 1);                // A(127) loaded at iter 125 (odd->pa)
    compute(0);                         // tile 126 (126%3 == 0)
    asm volatile("s_waitcnt lgkmcnt(0)" ::: "memory");
    __builtin_amdgcn_s_barrier();
    // tail t = 127
    compute(1);                         // tile 127 (127%3 == 1)

    // partial store: [block][64 rows][128 cols]; C: col=l15 base, row=lg*4+q
    float* pb = Pp + (size_t)blockIdx.x * (BM * BN);
#pragma unroll
    for (int q = 0; q < 4; ++q) {
        int r0 = wm * 32 + lg * 4 + q;
        int r1 = r0 + 16;
        pb[r0 * BN + n0] = acc00[q];
        pb[r0 * BN + nd] = acc01[q];
        pb[r1 * BN + n0] = acc10[q];
        pb[r1 * BN + nd] = acc11[q];
    }
}

// ---------------- Stage 5: combine K-halves, ratio + mu + bias ------------
__global__ __launch_bounds__(256) void reduce_kernel(
    const float* __restrict__ Pp, const float* __restrict__ bias,
    const float* __restrict__ muptr, float* __restrict__ out)
{
    int idx = blockIdx.x * 256 + threadIdx.x;   // 1M outputs
    int r = idx >> 6, c = idx & 63;
    int rb = r >> 6, rr = r & 63;
    const float* p0 = Pp + (size_t)(rb * 2) * (BM * BN) + rr * BN + c;
    const float* p1 = p0 + BM * BN;
    float T = p0[0]  + p1[0];
    float D = p0[64] + p1[64];
    out[idx] = T / D + muptr[0] + bias[c];
}

extern "C" void kernel_launch(void* const* d_in, const int* in_sizes, int n_in,
                              void* d_out, int out_size, void* d_ws, size_t ws_size,
                              hipStream_t stream)
{
    const float* inp  = (const float*)d_in[0];
    const float* adj  = (const float*)d_in[1];
    const float* W    = (const float*)d_in[2];
    const float* bias = (const float*)d_in[3];
    const int*   p    = (const int*)d_in[4];
    float* out = (float*)d_out;

    // ws layout: Bt 4MB | partmin 1KB | mu | Wt 64KB | (8MB:) Pp 16MB
    char* ws = (char*)d_ws;
    u16*   Bt      = (u16*)ws;
    float* partmin = (float*)(ws + (size_t)4 * 1024 * 1024);
    float* mu      = partmin + 256;
    float* Wt      = (float*)(ws + (size_t)4 * 1024 * 1024 + 4096);
    float* Pp      = (float*)(ws + (size_t)8 * 1024 * 1024);

    float* sup = out;   // park support in d_out; reduce overwrites at the end

    wt_kernel       <<<64,   256, 0, stream>>>(W, Wt);
    support_kernel  <<<512,  256, 0, stream>>>(inp, Wt, sup);
    min_part_kernel <<<256,  256, 0, stream>>>(sup, partmin);
    min_final_kernel<<<1,    256, 0, stream>>>(partmin, mu);
    build_bt_kernel <<<64,   256, 0, stream>>>(sup, mu, p, Bt);
    gemm_kernel     <<<512,  512, 0, stream>>>(adj, Bt, Pp);
    reduce_kernel   <<<4096, 256, 0, stream>>>(Pp, bias, mu, out);
}